// Round 2
// baseline (3483.256 us; speedup 1.0000x reference)
//
#include <hip/hip_runtime.h>
#include <hip/hip_bf16.h>

// B=8192, T=32, D_IN=2, EMB=128, H=256, 4H=1024
// 256 blocks x 1024 threads (16 waves); block owns 32 batch rows.
// Wave wid owns (w=wid>>2, s=wid&3): cols q*256 + w*64 + s*16 + [0,16), q=0..3 gates.
// MFMA 16x16x32 bf16 swapped operands: D = z^T tile, batch row in lane&15.

typedef __attribute__((ext_vector_type(8))) __bf16 bf16x8;
typedef __attribute__((ext_vector_type(4))) __bf16 bf16x4;
typedef __attribute__((ext_vector_type(4))) float f32x4;

#define MFMA16(a, b, c) __builtin_amdgcn_mfma_f32_16x16x32_bf16(a, b, c, 0, 0, 0)

__device__ __forceinline__ float fexp2(float x) {
#if __has_builtin(__builtin_amdgcn_exp2f)
  return __builtin_amdgcn_exp2f(x);
#else
  return exp2f(x);
#endif
}
__device__ __forceinline__ float frcp(float x) {
#if __has_builtin(__builtin_amdgcn_rcpf)
  return __builtin_amdgcn_rcpf(x);
#else
  return 1.0f / x;
#endif
}
__device__ __forceinline__ float fsig(float x) {
  return frcp(1.0f + fexp2(-1.44269504f * x));
}
__device__ __forceinline__ float ftanh(float x) {
  return 1.0f - 2.0f * frcp(1.0f + fexp2(2.88539008f * x));
}

// ---- weight prep: swizzle [W;U] (K x 1024) fp32 -> per-frag bf16 order ----
// L0: frag g = (wid*4+q)*12 + kc ; lane l elem j: k = kc*32+(l>>4)*8+j,
//     c = q*256 + (wid>>2)*64 + (wid&3)*16 + (l&15)
__global__ void prep_w0(const float* __restrict__ W0, const float* __restrict__ U0,
                        __bf16* __restrict__ o) {
  const int f = blockIdx.x * 256 + threadIdx.x;  // < 393216
  const int j = f & 7, l5 = (f >> 3) & 63, g = f >> 9;
  const int kc = g % 12, q = (g / 12) & 3, wid = g / 48;
  const int k = (kc << 5) + ((l5 >> 4) << 3) + j;
  const int c = (q << 8) + ((wid >> 2) << 6) + ((wid & 3) << 4) + (l5 & 15);
  const float v = (k < 128) ? W0[(k << 10) + c] : U0[((k - 128) << 10) + c];
  o[f] = (__bf16)v;
}
// L1: frag g = (wid*4+q)*16 + kcx (kcx=0..15; k = kcx*32+..., k<256 -> W1 else U1)
__global__ void prep_w1(const float* __restrict__ W1, const float* __restrict__ U1,
                        __bf16* __restrict__ o) {
  const int f = blockIdx.x * 256 + threadIdx.x;  // < 524288
  const int j = f & 7, l5 = (f >> 3) & 63, g = f >> 9;
  const int kcx = g & 15, q = (g >> 4) & 3, wid = g >> 6;
  const int k = (kcx << 5) + ((l5 >> 4) << 3) + j;
  const int c = (q << 8) + ((wid >> 2) << 6) + ((wid & 3) << 4) + (l5 & 15);
  const float v = (k < 256) ? W1[(k << 10) + c] : U1[((k - 256) << 10) + c];
  o[f] = (__bf16)v;
}

__global__ __launch_bounds__(1024)
void lstm_fused(const float* __restrict__ traj,
                const float* __restrict__ Wemb,
                const float* __restrict__ bemb,
                const float* __restrict__ bias0,
                const float* __restrict__ bias1,
                const __bf16* __restrict__ wb0,
                const __bf16* __restrict__ wb1,
                float* __restrict__ out) {
  __shared__ float s_We[384];       // We[0][:], We[1][:], be[:]
  __shared__ float s_b[2][1024];    // bias in (ct, cc) order
  __shared__ float s_traj[2048];    // transposed [t][r][d]
  __shared__ __bf16 s_h0[2][8192];  // [buf][r*256 + (e ^ ((r&7)<<3))]
  __shared__ __bf16 s_h1[2][8192];
  __shared__ float s_y[8192];       // fp32 h1 tile, [r*256 + (e ^ ((r&7)<<2))]

  const int tid = threadIdx.x;
  const int wid = tid >> 6;
  const int l = tid & 63;
  const int lr = l & 15, lg = l >> 4;
  const int w = wid >> 2, s4 = wid & 3;
  const int xr = (lr & 7) << 3;   // bf16-elem swizzle
  const int xrf = (lr & 7) << 2;  // f32-elem swizzle
  const int r0 = blockIdx.x << 5;

  if (tid < 384) s_We[tid] = (tid < 256) ? Wemb[tid] : bemb[tid - 256];
  {
    const int ct = tid >> 4, cc = tid & 15;
    const int wd = ct >> 2, q = ct & 3;
    const int col = (q << 8) + ((wd >> 2) << 6) + ((wd & 3) << 4) + cc;
    s_b[0][tid] = bias0[col];
    s_b[1][tid] = bias1[col];
  }
  for (int i = tid; i < 2048; i += 1024) {
    const int r = i >> 6, tt = (i >> 1) & 31, d = i & 1;
    s_traj[(tt << 6) + (r << 1) + d] = traj[(r0 << 6) + i];
  }
  for (int i = tid; i < 8192; i += 1024) {
    s_h0[0][i] = (__bf16)0.f;
    s_h1[0][i] = (__bf16)0.f;
  }
  __syncthreads();

  float c0s[2][4] = {};
  float c1s[2][4] = {};
  const __bf16* wp0 = wb0 + wid * 48 * 512 + l * 8;
  const __bf16* wp1 = wb1 + wid * 64 * 512 + l * 8;
  const int e0 = (w << 6) + (s4 << 4) + (lg << 2);

#pragma unroll 1
  for (int t = 0; t < 32; ++t) {
    const int cur = t & 1, nxt = cur ^ 1;

    {  // ---------------- layer 0: z = [x_t | h0] @ [W0;U0] + b0 ----------------
      f32x4 acc[4][2];
#pragma unroll
      for (int q = 0; q < 4; ++q) {
        const f32x4 b = *reinterpret_cast<const f32x4*>(
            &s_b[0][(((wid << 2) + q) << 4) + (lg << 2)]);
        acc[q][0] = b;
        acc[q][1] = b;
      }
#pragma unroll
      for (int kc = 0; kc < 4; ++kc) {  // x-part computed on the fly
        bf16x8 ia[2];
#pragma unroll
        for (int rt = 0; rt < 2; ++rt) {
          const int r = (rt << 4) + lr;
          const float t0 = s_traj[(t << 6) + (r << 1)];
          const float t1 = s_traj[(t << 6) + (r << 1) + 1];
#pragma unroll
          for (int j = 0; j < 8; ++j) {
            const int k = (kc << 5) + (lg << 3) + j;
            const float x = fmaf(t0, s_We[k], fmaf(t1, s_We[128 + k], s_We[256 + k]));
            ia[rt][j] = (__bf16)fmaxf(x, 0.f);
          }
        }
#pragma unroll
        for (int q = 0; q < 4; ++q) {
          const bf16x8 wf = *reinterpret_cast<const bf16x8*>(wp0 + (q * 12 + kc) * 512);
          acc[q][0] = MFMA16(wf, ia[0], acc[q][0]);
          acc[q][1] = MFMA16(wf, ia[1], acc[q][1]);
        }
      }
#pragma unroll
      for (int kc = 0; kc < 8; ++kc) {  // h0 part from LDS
        bf16x8 ia[2];
#pragma unroll
        for (int rt = 0; rt < 2; ++rt) {
          const int r = (rt << 4) + lr;
          const int idx = (r << 8) + (((kc << 5) + (lg << 3)) ^ xr);
          ia[rt] = *reinterpret_cast<const bf16x8*>(&s_h0[cur][idx]);
        }
#pragma unroll
        for (int q = 0; q < 4; ++q) {
          const bf16x8 wf = *reinterpret_cast<const bf16x8*>(wp0 + (q * 12 + 4 + kc) * 512);
          acc[q][0] = MFMA16(wf, ia[0], acc[q][0]);
          acc[q][1] = MFMA16(wf, ia[1], acc[q][1]);
        }
      }
#pragma unroll
      for (int rt = 0; rt < 2; ++rt) {
        const int r = (rt << 4) + lr;
        bf16x4 hv;
        f32x4 hfv, cfv;
#pragma unroll
        for (int i = 0; i < 4; ++i) {
          const float cc = fsig(acc[1][rt][i]) * c0s[rt][i] +
                           fsig(acc[0][rt][i]) * ftanh(acc[2][rt][i]);
          c0s[rt][i] = cc;
          const float hh = fsig(acc[3][rt][i]) * ftanh(cc);
          hv[i] = (__bf16)hh;
          hfv[i] = hh;
          cfv[i] = cc;
        }
        *reinterpret_cast<bf16x4*>(&s_h0[nxt][(r << 8) + (e0 ^ xr)]) = hv;
        if (t == 31) {
          const int base = ((r0 + r) << 8) + e0;
          __builtin_nontemporal_store(hfv, reinterpret_cast<f32x4*>(out + 67108864 + base));
          __builtin_nontemporal_store(cfv, reinterpret_cast<f32x4*>(out + 69206016 + base));
        }
      }
    }
    __syncthreads();

    {  // ---------------- layer 1: z = [h0_new | h1] @ [W1;U1] + b1 ----------------
      f32x4 acc[4][2];
#pragma unroll
      for (int q = 0; q < 4; ++q) {
        const f32x4 b = *reinterpret_cast<const f32x4*>(
            &s_b[1][(((wid << 2) + q) << 4) + (lg << 2)]);
        acc[q][0] = b;
        acc[q][1] = b;
      }
#pragma unroll
      for (int hf2 = 0; hf2 < 2; ++hf2) {
        const __bf16* src = hf2 ? s_h1[cur] : s_h0[nxt];
#pragma unroll
        for (int kc = 0; kc < 8; ++kc) {
          bf16x8 ib[2];
#pragma unroll
          for (int rt = 0; rt < 2; ++rt) {
            const int r = (rt << 4) + lr;
            const int idx = (r << 8) + (((kc << 5) + (lg << 3)) ^ xr);
            ib[rt] = *reinterpret_cast<const bf16x8*>(&src[idx]);
          }
#pragma unroll
          for (int q = 0; q < 4; ++q) {
            const bf16x8 wf = *reinterpret_cast<const bf16x8*>(
                wp1 + (q * 16 + hf2 * 8 + kc) * 512);
            acc[q][0] = MFMA16(wf, ib[0], acc[q][0]);
            acc[q][1] = MFMA16(wf, ib[1], acc[q][1]);
          }
        }
      }
#pragma unroll
      for (int rt = 0; rt < 2; ++rt) {
        const int r = (rt << 4) + lr;
        bf16x4 hv;
        f32x4 hfv, cfv;
#pragma unroll
        for (int i = 0; i < 4; ++i) {
          const float cc = fsig(acc[1][rt][i]) * c1s[rt][i] +
                           fsig(acc[0][rt][i]) * ftanh(acc[2][rt][i]);
          c1s[rt][i] = cc;
          const float hh = fsig(acc[3][rt][i]) * ftanh(cc);
          hv[i] = (__bf16)hh;
          hfv[i] = hh;
          cfv[i] = cc;
        }
        *reinterpret_cast<bf16x4*>(&s_h1[nxt][(r << 8) + (e0 ^ xr)]) = hv;
        *reinterpret_cast<f32x4*>(&s_y[(r << 8) + (e0 ^ xrf)]) = hfv;
        if (t == 31) {
          const int base = ((r0 + r) << 8) + e0;
          __builtin_nontemporal_store(cfv, reinterpret_cast<f32x4*>(out + 73400320 + base));
        }
      }
    }
    __syncthreads();

    {  // ---------------- coalesced y write (reads s_y of this t) ----------------
      const int row = tid >> 5;
      const int off = (tid & 31) << 3;
      const int xw = (row & 7) << 2;
      const f32x4 v0 = *reinterpret_cast<const f32x4*>(&s_y[(row << 8) + (off ^ xw)]);
      const f32x4 v1 = *reinterpret_cast<const f32x4*>(&s_y[(row << 8) + ((off + 4) ^ xw)]);
      float* gp = out + ((((r0 + row) << 5) + t) << 8) + off;
      __builtin_nontemporal_store(v0, reinterpret_cast<f32x4*>(gp));
      __builtin_nontemporal_store(v1, reinterpret_cast<f32x4*>(gp + 4));
      if (t == 31) {  // h1 final = y1[:, 31, :]
        float* fp = out + 71303168 + ((r0 + row) << 8) + off;
        __builtin_nontemporal_store(v0, reinterpret_cast<f32x4*>(fp));
        __builtin_nontemporal_store(v1, reinterpret_cast<f32x4*>(fp + 4));
      }
      // no barrier needed: next write of s_y is after the next layer-0 barrier
    }
  }
}

extern "C" void kernel_launch(void* const* d_in, const int* in_sizes, int n_in,
                              void* d_out, int out_size, void* d_ws, size_t ws_size,
                              hipStream_t stream) {
  const float* traj = (const float*)d_in[0];
  const float* Wemb = (const float*)d_in[1];
  const float* bemb = (const float*)d_in[2];
  const float* W0 = (const float*)d_in[3];
  const float* U0 = (const float*)d_in[4];
  const float* b0 = (const float*)d_in[5];
  const float* W1 = (const float*)d_in[6];
  const float* U1 = (const float*)d_in[7];
  const float* b1 = (const float*)d_in[8];
  float* out = (float*)d_out;

  __bf16* wb0 = (__bf16*)d_ws;  // 393216 elems = 768 KB
  __bf16* wb1 = wb0 + 393216;   // 524288 elems = 1 MB

  hipLaunchKernelGGL(prep_w0, dim3(1536), dim3(256), 0, stream, W0, U0, wb0);
  hipLaunchKernelGGL(prep_w1, dim3(2048), dim3(256), 0, stream, W1, U1, wb1);
  hipLaunchKernelGGL(lstm_fused, dim3(256), dim3(1024), 0, stream,
                     traj, Wemb, bemb, b0, b1, wb0, wb1, out);
}

// Round 3
// 2759.459 us; speedup vs baseline: 1.2623x; 1.2623x over previous
//
#include <hip/hip_runtime.h>
#include <hip/hip_bf16.h>

// B=8192, T=32, D_IN=2, EMB=128, H=256, 4H=1024
// 128 blocks x 1024 threads (16 waves); block owns 64 batch rows.
// Wave wid owns (w=wid>>2, s=wid&3): cols q*256 + w*64 + s*16 + [0,16), q=0..3 gates.
// MFMA 16x16x32 bf16 swapped operands: D = z^T tile, batch row in lane&15; 4 row-tiles.

typedef __attribute__((ext_vector_type(8))) __bf16 bf16x8;
typedef __attribute__((ext_vector_type(4))) __bf16 bf16x4;
typedef __attribute__((ext_vector_type(4))) float f32x4;

#define MFMA16(a, b, c) __builtin_amdgcn_mfma_f32_16x16x32_bf16(a, b, c, 0, 0, 0)

__device__ __forceinline__ float fexp2(float x) {
#if __has_builtin(__builtin_amdgcn_exp2f)
  return __builtin_amdgcn_exp2f(x);
#else
  return exp2f(x);
#endif
}
__device__ __forceinline__ float frcp(float x) {
#if __has_builtin(__builtin_amdgcn_rcpf)
  return __builtin_amdgcn_rcpf(x);
#else
  return 1.0f / x;
#endif
}
__device__ __forceinline__ float fsig(float x) {
  return frcp(1.0f + fexp2(-1.44269504f * x));
}
__device__ __forceinline__ float ftanh(float x) {
  return 1.0f - 2.0f * frcp(1.0f + fexp2(2.88539008f * x));
}

// ---- weight prep: swizzle [W;U] (K x 1024) fp32 -> per-frag bf16 order ----
// L0: frag g = (wid*4+q)*12 + kc ; lane l elem j: k = kc*32+(l>>4)*8+j,
//     c = q*256 + (wid>>2)*64 + (wid&3)*16 + (l&15)
__global__ void prep_w0(const float* __restrict__ W0, const float* __restrict__ U0,
                        __bf16* __restrict__ o) {
  const int f = blockIdx.x * 256 + threadIdx.x;  // < 393216
  const int j = f & 7, l5 = (f >> 3) & 63, g = f >> 9;
  const int kc = g % 12, q = (g / 12) & 3, wid = g / 48;
  const int k = (kc << 5) + ((l5 >> 4) << 3) + j;
  const int c = (q << 8) + ((wid >> 2) << 6) + ((wid & 3) << 4) + (l5 & 15);
  const float v = (k < 128) ? W0[(k << 10) + c] : U0[((k - 128) << 10) + c];
  o[f] = (__bf16)v;
}
// L1: frag g = (wid*4+q)*16 + kcx (kcx=0..15; k = kcx*32+..., k<256 -> W1 else U1)
__global__ void prep_w1(const float* __restrict__ W1, const float* __restrict__ U1,
                        __bf16* __restrict__ o) {
  const int f = blockIdx.x * 256 + threadIdx.x;  // < 524288
  const int j = f & 7, l5 = (f >> 3) & 63, g = f >> 9;
  const int kcx = g & 15, q = (g >> 4) & 3, wid = g >> 6;
  const int k = (kcx << 5) + ((l5 >> 4) << 3) + j;
  const int c = (q << 8) + ((wid >> 2) << 6) + ((wid & 3) << 4) + (l5 & 15);
  const float v = (k < 256) ? W1[(k << 10) + c] : U1[((k - 256) << 10) + c];
  o[f] = (__bf16)v;
}

__global__ __launch_bounds__(1024)
void lstm_fused(const float* __restrict__ traj,
                const float* __restrict__ Wemb,
                const float* __restrict__ bemb,
                const float* __restrict__ bias0,
                const float* __restrict__ bias1,
                const __bf16* __restrict__ wb0,
                const __bf16* __restrict__ wb1,
                float* __restrict__ out) {
  __shared__ float s_We[384];        // We[0][:], We[1][:], be[:]
  __shared__ float s_b[2][1024];     // bias in (ct, cc) order
  __shared__ float s_traj[4096];     // [t][r][d]: t*128 + r*2 + d
  __shared__ __bf16 s_h0[2][16384];  // [buf][r*256 + (e ^ ((r&7)<<3))]
  __shared__ __bf16 s_h1[2][16384];

  const int tid = threadIdx.x;
  const int wid = tid >> 6;
  const int l = tid & 63;
  const int lr = l & 15, lg = l >> 4;
  const int w = wid >> 2, s4 = wid & 3;
  const int xr = (lr & 7) << 3;  // bf16-elem swizzle, fn of row only
  const int r0 = blockIdx.x << 6;

  if (tid < 384) s_We[tid] = (tid < 256) ? Wemb[tid] : bemb[tid - 256];
  {
    const int ct = tid >> 4, cc = tid & 15;
    const int wd = ct >> 2, q = ct & 3;
    const int col = (q << 8) + ((wd >> 2) << 6) + ((wd & 3) << 4) + cc;
    s_b[0][tid] = bias0[col];
    s_b[1][tid] = bias1[col];
  }
  for (int i = tid; i < 4096; i += 1024) {
    const int r = i >> 6, tt = (i >> 1) & 31, d = i & 1;
    s_traj[(tt << 7) + (r << 1) + d] = traj[(r0 << 6) + i];
  }
  for (int i = tid; i < 16384; i += 1024) {
    s_h0[0][i] = (__bf16)0.f;
    s_h1[0][i] = (__bf16)0.f;
  }
  __syncthreads();

  float c0s[4][4] = {};
  float c1s[4][4] = {};
  const __bf16* wp0 = wb0 + wid * 48 * 512 + l * 8;
  const __bf16* wp1 = wb1 + wid * 64 * 512 + l * 8;
  const int e0 = (w << 6) + (s4 << 4) + (lg << 2);

#pragma unroll 1
  for (int t = 0; t < 32; ++t) {
    const int cur = t & 1, nxt = cur ^ 1;

    {  // ---------------- layer 0: z = [x_t | h0] @ [W0;U0] + b0 ----------------
      f32x4 acc[4][4];  // [q][rt]
#pragma unroll
      for (int q = 0; q < 4; ++q) {
        const f32x4 b = *reinterpret_cast<const f32x4*>(
            &s_b[0][(((wid << 2) + q) << 4) + (lg << 2)]);
#pragma unroll
        for (int rt = 0; rt < 4; ++rt) acc[q][rt] = b;
      }
      float t0v[4], t1v[4];
#pragma unroll
      for (int rt = 0; rt < 4; ++rt) {
        const int r = (rt << 4) + lr;
        t0v[rt] = s_traj[(t << 7) + (r << 1)];
        t1v[rt] = s_traj[(t << 7) + (r << 1) + 1];
      }
#pragma unroll
      for (int kc = 0; kc < 4; ++kc) {  // x-part computed on the fly
        bf16x8 ia[4];
#pragma unroll
        for (int rt = 0; rt < 4; ++rt) {
#pragma unroll
          for (int j = 0; j < 8; ++j) {
            const int k = (kc << 5) + (lg << 3) + j;
            const float x =
                fmaf(t0v[rt], s_We[k], fmaf(t1v[rt], s_We[128 + k], s_We[256 + k]));
            ia[rt][j] = (__bf16)fmaxf(x, 0.f);
          }
        }
#pragma unroll
        for (int q = 0; q < 4; ++q) {
          const bf16x8 wf = *reinterpret_cast<const bf16x8*>(wp0 + (q * 12 + kc) * 512);
#pragma unroll
          for (int rt = 0; rt < 4; ++rt) acc[q][rt] = MFMA16(wf, ia[rt], acc[q][rt]);
        }
      }
#pragma unroll
      for (int kc = 0; kc < 8; ++kc) {  // h0 part from LDS
        bf16x8 ia[4];
#pragma unroll
        for (int rt = 0; rt < 4; ++rt) {
          const int r = (rt << 4) + lr;
          const int idx = (r << 8) + (((kc << 5) + (lg << 3)) ^ xr);
          ia[rt] = *reinterpret_cast<const bf16x8*>(&s_h0[cur][idx]);
        }
#pragma unroll
        for (int q = 0; q < 4; ++q) {
          const bf16x8 wf =
              *reinterpret_cast<const bf16x8*>(wp0 + (q * 12 + 4 + kc) * 512);
#pragma unroll
          for (int rt = 0; rt < 4; ++rt) acc[q][rt] = MFMA16(wf, ia[rt], acc[q][rt]);
        }
      }
#pragma unroll
      for (int rt = 0; rt < 4; ++rt) {
        const int r = (rt << 4) + lr;
        bf16x4 hv;
        f32x4 hfv, cfv;
#pragma unroll
        for (int i = 0; i < 4; ++i) {
          const float cc = fsig(acc[1][rt][i]) * c0s[rt][i] +
                           fsig(acc[0][rt][i]) * ftanh(acc[2][rt][i]);
          c0s[rt][i] = cc;
          const float hh = fsig(acc[3][rt][i]) * ftanh(cc);
          hv[i] = (__bf16)hh;
          hfv[i] = hh;
          cfv[i] = cc;
        }
        *reinterpret_cast<bf16x4*>(&s_h0[nxt][(r << 8) + (e0 ^ xr)]) = hv;
        if (t == 31) {
          const int base = ((r0 + r) << 8) + e0;
          *reinterpret_cast<f32x4*>(out + 67108864 + base) = hfv;  // h0 final
          *reinterpret_cast<f32x4*>(out + 69206016 + base) = cfv;  // c0 final
        }
      }
    }
    __syncthreads();

    {  // ---------------- layer 1: z = [h0_new | h1] @ [W1;U1] + b1 ----------------
      f32x4 acc[4][4];
#pragma unroll
      for (int q = 0; q < 4; ++q) {
        const f32x4 b = *reinterpret_cast<const f32x4*>(
            &s_b[1][(((wid << 2) + q) << 4) + (lg << 2)]);
#pragma unroll
        for (int rt = 0; rt < 4; ++rt) acc[q][rt] = b;
      }
#pragma unroll
      for (int hf2 = 0; hf2 < 2; ++hf2) {
        const __bf16* src = hf2 ? s_h1[cur] : s_h0[nxt];
#pragma unroll
        for (int kc = 0; kc < 8; ++kc) {
          bf16x8 ib[4];
#pragma unroll
          for (int rt = 0; rt < 4; ++rt) {
            const int r = (rt << 4) + lr;
            const int idx = (r << 8) + (((kc << 5) + (lg << 3)) ^ xr);
            ib[rt] = *reinterpret_cast<const bf16x8*>(&src[idx]);
          }
#pragma unroll
          for (int q = 0; q < 4; ++q) {
            const bf16x8 wf = *reinterpret_cast<const bf16x8*>(
                wp1 + (q * 16 + hf2 * 8 + kc) * 512);
#pragma unroll
            for (int rt = 0; rt < 4; ++rt) acc[q][rt] = MFMA16(wf, ib[rt], acc[q][rt]);
          }
        }
      }
#pragma unroll
      for (int rt = 0; rt < 4; ++rt) {
        const int r = (rt << 4) + lr;
        bf16x4 hv;
        f32x4 cfv;
#pragma unroll
        for (int i = 0; i < 4; ++i) {
          const float cc = fsig(acc[1][rt][i]) * c1s[rt][i] +
                           fsig(acc[0][rt][i]) * ftanh(acc[2][rt][i]);
          c1s[rt][i] = cc;
          const float hh = fsig(acc[3][rt][i]) * ftanh(cc);
          hv[i] = (__bf16)hh;
          cfv[i] = cc;
        }
        *reinterpret_cast<bf16x4*>(&s_h1[nxt][(r << 8) + (e0 ^ xr)]) = hv;
        if (t == 31) {
          const int base = ((r0 + r) << 8) + e0;
          *reinterpret_cast<f32x4*>(out + 73400320 + base) = cfv;  // c1 final
        }
      }
    }
    __syncthreads();

    {  // ---- coalesced y write: each lane owns a full 64B line segment ----
      // row = tid>>4 (64 rows), lane covers floats [16*(tid&15), +16)
      const int row = tid >> 4, cl = tid & 15;
      const int xw = (row & 7) << 3;
      const __bf16* hp = &s_h1[nxt][row << 8];
      const bf16x8 a = *reinterpret_cast<const bf16x8*>(&hp[(cl << 4) ^ xw]);
      const bf16x8 b = *reinterpret_cast<const bf16x8*>(&hp[((cl << 4) + 8) ^ xw]);
      f32x4 v0, v1, v2, v3;
#pragma unroll
      for (int i = 0; i < 4; ++i) {
        v0[i] = (float)a[i];
        v1[i] = (float)a[4 + i];
        v2[i] = (float)b[i];
        v3[i] = (float)b[4 + i];
      }
      float* gp = out + ((((r0 + row) << 5) + t) << 8) + (cl << 4);
      *reinterpret_cast<f32x4*>(gp) = v0;
      *reinterpret_cast<f32x4*>(gp + 4) = v1;
      *reinterpret_cast<f32x4*>(gp + 8) = v2;
      *reinterpret_cast<f32x4*>(gp + 12) = v3;
      if (t == 31) {  // h1 final = y1[:, 31, :]
        float* fp = out + 71303168 + ((r0 + row) << 8) + (cl << 4);
        *reinterpret_cast<f32x4*>(fp) = v0;
        *reinterpret_cast<f32x4*>(fp + 4) = v1;
        *reinterpret_cast<f32x4*>(fp + 8) = v2;
        *reinterpret_cast<f32x4*>(fp + 12) = v3;
      }
      // no barrier needed: s_h1[nxt] is next written at t+2, behind two barriers
    }
  }
}

extern "C" void kernel_launch(void* const* d_in, const int* in_sizes, int n_in,
                              void* d_out, int out_size, void* d_ws, size_t ws_size,
                              hipStream_t stream) {
  const float* traj = (const float*)d_in[0];
  const float* Wemb = (const float*)d_in[1];
  const float* bemb = (const float*)d_in[2];
  const float* W0 = (const float*)d_in[3];
  const float* U0 = (const float*)d_in[4];
  const float* b0 = (const float*)d_in[5];
  const float* W1 = (const float*)d_in[6];
  const float* U1 = (const float*)d_in[7];
  const float* b1 = (const float*)d_in[8];
  float* out = (float*)d_out;

  __bf16* wb0 = (__bf16*)d_ws;  // 393216 elems = 768 KB
  __bf16* wb1 = wb0 + 393216;   // 524288 elems = 1 MB

  hipLaunchKernelGGL(prep_w0, dim3(1536), dim3(256), 0, stream, W0, U0, wb0);
  hipLaunchKernelGGL(prep_w1, dim3(2048), dim3(256), 0, stream, W1, U1, wb1);
  hipLaunchKernelGGL(lstm_fused, dim3(128), dim3(1024), 0, stream,
                     traj, Wemb, bemb, b0, b1, wb0, wb1, out);
}